// Round 2
// baseline (194.077 us; speedup 1.0000x reference)
//
#include <hip/hip_runtime.h>
#include <hip/hip_bf16.h>

// Problem: B=1024, S=128, E=256, H=2, DH=128.  vp (V projection) is dead code
// in the reference -> never read v/Wv/bv.
// out[b,s,e] = (P @ Wo + bo),  P[s, h*128+j] = softmax_j( (q@Wq+bq)/16 [s, h*128+m]
//                                   dot  (k@Wk+bk)[m, h*128+j]  + (mask[b,j]==0) )
#define NB 1024
#define NS 128
#define NE 256

typedef __attribute__((ext_vector_type(8))) short bf16x8;
typedef __attribute__((ext_vector_type(4))) float f32x4;

__device__ __forceinline__ unsigned short f2bf(float x) {
  unsigned int u = __float_as_uint(x);
  u = (u + 0x7fffu + ((u >> 16) & 1u)) >> 16;   // RNE
  return (unsigned short)u;
}

// WT[n][k] = W[k][n]  (bf16) -- B-operand wants [N][K] contiguous-K rows.
__global__ void prep_weights(const float* __restrict__ Wq,
                             const float* __restrict__ Wk,
                             const float* __restrict__ Wo,
                             short* __restrict__ WqT,
                             short* __restrict__ WkT,
                             short* __restrict__ WoT) {
  int idx = blockIdx.x * blockDim.x + threadIdx.x;  // = n*256 + k
  int n = idx >> 8;
  int kk = idx & 255;
  WqT[idx] = (short)f2bf(Wq[kk * NE + n]);
  WkT[idx] = (short)f2bf(Wk[kk * NE + n]);
  WoT[idx] = (short)f2bf(Wo[kk * NE + n]);
}

// Stage a 128x256 f32 global tile into LDS as bf16, rows of 512B,
// XOR-swizzled: byte_in_row ^= (row&7)<<4  (kills the stride-512B 16-way
// bank conflict on ds_read_b128 A-fragment reads).
__device__ __forceinline__ void stage_tile(const float* __restrict__ src,
                                           char* __restrict__ dst, int t) {
  #pragma unroll
  for (int i = 0; i < 16; ++i) {
    int idx = t + i * 512;                       // float4 index, coalesced 1KB/wave
    float4 v = reinterpret_cast<const float4*>(src)[idx];
    int row = idx >> 6;                          // 64 float4 per row
    int colb = (idx & 63) << 3;                  // byte offset within row
    ushort4 u;
    u.x = f2bf(v.x); u.y = f2bf(v.y); u.z = f2bf(v.z); u.w = f2bf(v.w);
    *reinterpret_cast<ushort4*>(dst + row * 512 + (colb ^ ((row & 7) << 4))) = u;
  }
}

// 128x256 = A(128x256, LDS swizzled bf16) @ B(256x256, global bf16 [N][K]).
// Wave grid 2x4: wave (wr,wc) owns 4 row-tiles x 4 col-tiles of 16x16.
// B-fragments reused across 4 row-tiles (cuts L2 weight traffic 4x).
__device__ __forceinline__ void gemm_8x16(const char* __restrict__ ldsA,
                                          const short* __restrict__ BT,
                                          int wr, int wc, int cl, int c4,
                                          f32x4 acc[4][4]) {
  #pragma unroll
  for (int ks = 0; ks < 8; ++ks) {
    const int kel = ks * 32 + 8 * c4;            // lane's 8 contiguous k elems
    bf16x8 a[4], bb[4];
    #pragma unroll
    for (int mi = 0; mi < 4; ++mi) {
      int row = wr * 64 + mi * 16 + cl;
      a[mi] = *reinterpret_cast<const bf16x8*>(
          ldsA + row * 512 + ((kel * 2) ^ ((row & 7) << 4)));
    }
    #pragma unroll
    for (int ni = 0; ni < 4; ++ni) {
      int col = wc * 64 + ni * 16 + cl;
      bb[ni] = *reinterpret_cast<const bf16x8*>(BT + col * 256 + kel);
    }
    #pragma unroll
    for (int mi = 0; mi < 4; ++mi)
      #pragma unroll
      for (int ni = 0; ni < 4; ++ni)
        acc[mi][ni] = __builtin_amdgcn_mfma_f32_16x16x32_bf16(
            a[mi], bb[ni], acc[mi][ni], 0, 0, 0);
  }
}

__global__ __launch_bounds__(512, 2)
void fused_attn(const float* __restrict__ q,
                const float* __restrict__ kin,
                const int* __restrict__ am,
                const float* __restrict__ bq,
                const float* __restrict__ bk,
                const float* __restrict__ bo,
                const short* __restrict__ WqT,
                const short* __restrict__ WkT,
                const short* __restrict__ WoT,
                float* __restrict__ out) {
  extern __shared__ char lds[];
  char* stA = lds;           // 64KB: staged k -> staged q -> qp -> probs
  char* kpT = lds + 65536;   // 64KB: [h][dh j][seq] bf16, swizzled rows of 256B

  const int t = threadIdx.x;
  const int lane = t & 63;
  const int wid = t >> 6;     // 8 waves
  const int cl = lane & 15;
  const int c4 = lane >> 4;
  const int wr = wid >> 2;    // 0..1
  const int wc = wid & 3;     // 0..3
  const int b = blockIdx.x;

  f32x4 acc[4][4];

  // ---- P1: stage K as bf16 ----
  stage_tile(kin + (size_t)b * (NS * NE), stA, t);
  __syncthreads();

  // ---- P2: kp = k @ Wk + bk ; store transposed per head into kpT ----
  #pragma unroll
  for (int mi = 0; mi < 4; ++mi)
    #pragma unroll
    for (int ni = 0; ni < 4; ++ni) acc[mi][ni] = (f32x4){0.f, 0.f, 0.f, 0.f};
  gemm_8x16(stA, WkT, wr, wc, cl, c4, acc);
  #pragma unroll
  for (int mi = 0; mi < 4; ++mi)
    #pragma unroll
    for (int ni = 0; ni < 4; ++ni) {
      int ce = wc * 64 + ni * 16 + cl;           // E column
      float bkv = bk[ce];
      int h = ce >> 7, j = ce & 127;
      char* base = kpT + h * 32768 + j * 256;    // row = dh j, col = seq
      int sw = (j & 7) << 4;
      #pragma unroll
      for (int r = 0; r < 4; ++r) {
        int seq = wr * 64 + mi * 16 + c4 * 4 + r;
        *reinterpret_cast<unsigned short*>(base + ((seq * 2) ^ sw)) =
            f2bf(acc[mi][ni][r] + bkv);
      }
    }
  __syncthreads();

  // ---- P3: stage Q over the k staging area ----
  stage_tile(q + (size_t)b * (NS * NE), stA, t);
  __syncthreads();

  // ---- P4: qp = (q @ Wq + bq) * (1/16); write back over stA ----
  #pragma unroll
  for (int mi = 0; mi < 4; ++mi)
    #pragma unroll
    for (int ni = 0; ni < 4; ++ni) acc[mi][ni] = (f32x4){0.f, 0.f, 0.f, 0.f};
  gemm_8x16(stA, WqT, wr, wc, cl, c4, acc);
  __syncthreads();   // every wave done READING q before anyone overwrites
  #pragma unroll
  for (int mi = 0; mi < 4; ++mi)
    #pragma unroll
    for (int ni = 0; ni < 4; ++ni) {
      int ce = wc * 64 + ni * 16 + cl;
      float bqv = bq[ce];
      int ceb = ce * 2;
      #pragma unroll
      for (int r = 0; r < 4; ++r) {
        int seq = wr * 64 + mi * 16 + c4 * 4 + r;
        *reinterpret_cast<unsigned short*>(
            stA + seq * 512 + (ceb ^ ((seq & 7) << 4))) =
            f2bf((acc[mi][ni][r] + bqv) * 0.0625f);
      }
    }
  __syncthreads();

  // ---- P5: scores = qh @ kh (+mask) -> softmax -> probs (bf16, back to stA)
  // Wave `wid` owns seq rows [wid*16, wid*16+16): reads/writes are wave-private.
  {
    f32x4 sacc[2][8];
    #pragma unroll
    for (int h = 0; h < 2; ++h)
      #pragma unroll
      for (int ni = 0; ni < 8; ++ni) sacc[h][ni] = (f32x4){0.f, 0.f, 0.f, 0.f};
    const int arow = wid * 16 + cl;
    #pragma unroll
    for (int h = 0; h < 2; ++h) {
      #pragma unroll
      for (int ks = 0; ks < 4; ++ks) {
        int kel = h * 128 + ks * 32 + 8 * c4;    // col in qp (A k-index)
        bf16x8 a = *reinterpret_cast<const bf16x8*>(
            stA + arow * 512 + ((kel * 2) ^ ((arow & 7) << 4)));
        int kb = (ks * 32 + 8 * c4) * 2;         // byte offset in kpT row (seq)
        #pragma unroll
        for (int ni = 0; ni < 8; ++ni) {
          int jr = ni * 16 + cl;                 // dh j (B n-index)
          bf16x8 bbv = *reinterpret_cast<const bf16x8*>(
              kpT + h * 32768 + jr * 256 + (kb ^ ((jr & 7) << 4)));
          sacc[h][ni] = __builtin_amdgcn_mfma_f32_16x16x32_bf16(
              a, bbv, sacc[h][ni], 0, 0, 0);
        }
      }
    }
    // mask add: +1.0 where attention_mask[b][j]==0 (same for both heads)
    float madd[8];
    #pragma unroll
    for (int ni = 0; ni < 8; ++ni)
      madd[ni] = (am[b * NS + ni * 16 + cl] == 0) ? 1.0f : 0.0f;
    // wave-parallel softmax along j: in-lane over 8 tiles, then shfl_xor
    // across the 16 lanes (cl) sharing this row group.
    #pragma unroll
    for (int h = 0; h < 2; ++h) {
      #pragma unroll
      for (int r = 0; r < 4; ++r) {
        float m = -1e30f;
        #pragma unroll
        for (int ni = 0; ni < 8; ++ni) m = fmaxf(m, sacc[h][ni][r] + madd[ni]);
        #pragma unroll
        for (int d = 1; d < 16; d <<= 1) m = fmaxf(m, __shfl_xor(m, d, 64));
        float s = 0.f;
        #pragma unroll
        for (int ni = 0; ni < 8; ++ni) {
          float e = __expf(sacc[h][ni][r] + madd[ni] - m);
          sacc[h][ni][r] = e;
          s += e;
        }
        #pragma unroll
        for (int d = 1; d < 16; d <<= 1) s += __shfl_xor(s, d, 64);
        float rinv = 1.0f / s;
        #pragma unroll
        for (int ni = 0; ni < 8; ++ni) sacc[h][ni][r] *= rinv;
      }
    }
    // write probs bf16: stA[seq][h*128+j]  (this wave's own rows only)
    #pragma unroll
    for (int h = 0; h < 2; ++h)
      #pragma unroll
      for (int ni = 0; ni < 8; ++ni)
        #pragma unroll
        for (int r = 0; r < 4; ++r) {
          int seq = wid * 16 + c4 * 4 + r;
          int ceb = (h * 128 + ni * 16 + cl) * 2;
          *reinterpret_cast<unsigned short*>(
              stA + seq * 512 + (ceb ^ ((seq & 7) << 4))) =
              f2bf(sacc[h][ni][r]);
        }
  }
  __syncthreads();

  // ---- P6: out = P @ Wo + bo ----
  #pragma unroll
  for (int mi = 0; mi < 4; ++mi)
    #pragma unroll
    for (int ni = 0; ni < 4; ++ni) acc[mi][ni] = (f32x4){0.f, 0.f, 0.f, 0.f};
  gemm_8x16(stA, WoT, wr, wc, cl, c4, acc);
  float* ob = out + (size_t)b * (NS * NE);
  #pragma unroll
  for (int mi = 0; mi < 4; ++mi)
    #pragma unroll
    for (int ni = 0; ni < 4; ++ni) {
      int ce = wc * 64 + ni * 16 + cl;
      float bov = bo[ce];
      #pragma unroll
      for (int r = 0; r < 4; ++r) {
        int seq = wr * 64 + mi * 16 + c4 * 4 + r;
        ob[seq * NE + ce] = acc[mi][ni][r] + bov;
      }
    }
}

extern "C" void kernel_launch(void* const* d_in, const int* in_sizes, int n_in,
                              void* d_out, int out_size, void* d_ws, size_t ws_size,
                              hipStream_t stream) {
  const float* q  = (const float*)d_in[0];
  const float* k  = (const float*)d_in[1];
  // d_in[2] = v : dead in the reference, never touched
  const int*   am = (const int*)d_in[3];
  const float* Wq = (const float*)d_in[4];
  const float* bq = (const float*)d_in[5];
  const float* Wk = (const float*)d_in[6];
  const float* bk = (const float*)d_in[7];
  // d_in[8] = Wv, d_in[9] = bv : dead
  const float* Wo = (const float*)d_in[10];
  const float* bo = (const float*)d_in[11];
  float* out = (float*)d_out;

  // workspace: 3 x 256x256 bf16 transposed weights = 384KB
  short* WqT = (short*)d_ws;
  short* WkT = WqT + NE * NE;
  short* WoT = WkT + NE * NE;

  prep_weights<<<NE * NE / 256, 256, 0, stream>>>(Wq, Wk, Wo, WqT, WkT, WoT);

  // 128KB dynamic LDS (gfx950 has 160KB/CU); request the cap in case the
  // runtime enforces the 64KB default. Ignore failure (ROCm typically
  // allows large dynamic LDS at launch without the opt-in).
  (void)hipFuncSetAttribute((const void*)fused_attn,
                            hipFuncAttributeMaxDynamicSharedMemorySize, 131072);
  fused_attn<<<NB, 512, 131072, stream>>>(q, k, am, bq, bk, bo,
                                          WqT, WkT, WoT, out);
}